// Round 16
// baseline (354.972 us; speedup 1.0000x reference)
//
#include <hip/hip_runtime.h>
#include <hip/hip_bf16.h>

#define B_ROWS 32768
#define NDEPTH 5

typedef float  f32x16 __attribute__((ext_vector_type(16)));
typedef short  bf16x8 __attribute__((ext_vector_type(8)));
typedef unsigned short ushort8v __attribute__((ext_vector_type(8)));

__device__ __forceinline__ unsigned short f2bf(float f) {
    __hip_bfloat16 h = __float2bfloat16(f);   // RNE; v_cvt_pk_bf16_f32
    return __builtin_bit_cast(unsigned short, h);
}

// division-free gates: v_exp + v_rcp only (R15-verified)
__device__ __forceinline__ float fast_sig(float x) {
    x = fminf(fmaxf(x, -30.f), 30.f);
    float e = __expf(-x);
    return __builtin_amdgcn_rcpf(1.0f + e);
}
__device__ __forceinline__ float fast_tanh(float x) {
    x = fminf(fmaxf(x, -15.f), 15.f);
    float e = __expf(2.0f * x);
    return 1.0f - 2.0f * __builtin_amdgcn_rcpf(e + 1.0f);
}

// ---- ONE prep launch: state-pack (R13-verified body) + weight-pack (R8-verified body) ----
// blocks [0, 11264): pack states; blocks [11264, 11840): 4 weight tiles each (64 lanes/tile).
__global__ void __launch_bounds__(256, 2)
prep_all(const float* __restrict__ sHyper, const float* __restrict__ sNetwork,
         const float* __restrict__ x,
         const float* __restrict__ Wch, const float* __restrict__ Wup,
         const float* __restrict__ Wcn, const float* __restrict__ Wih,
         const float* __restrict__ Win,
         unsigned short* __restrict__ pH, unsigned short* __restrict__ pN,
         unsigned short* __restrict__ pX,
         unsigned short* __restrict__ pCH, unsigned short* __restrict__ pUP,
         unsigned short* __restrict__ pCN, unsigned short* __restrict__ pIH,
         unsigned short* __restrict__ pIN) {
    __shared__ float ldsf[32 * 257];
    if (blockIdx.x < 11264) {
        // ---------- state pack (R13 spack verbatim) ----------
        int t = blockIdx.x;
        const float* src; unsigned short* out; int K;
        if (t < 5120)        {             src = sHyper;   out = pH; K = 128; }
        else if (t < 10240)  { t -= 5120;  src = sNetwork; out = pN; K = 256; }
        else                 { t -= 10240; src = x;        out = pX; K = 256; }
        const int NKS = K / 16, KP = K + 1;
        const float* in = src + (size_t)t * 32 * K;
        const int tid = threadIdx.x, w = tid >> 6, lane = tid & 63;
        const int lc = lane & 31, hi = lane >> 5;

        if (K == 256) {
#pragma unroll
            for (int it = 0; it < 8; ++it) {
                int u = it * 256 + tid;
                int row = u >> 6, seg = u & 63;
                *(float4*)&ldsf[row * KP + seg * 4] = *(const float4*)(in + (size_t)row * K + seg * 4);
            }
        } else {
#pragma unroll
            for (int it = 0; it < 4; ++it) {
                int u = it * 256 + tid;
                int row = u >> 5, seg = u & 31;
                *(float4*)&ldsf[row * KP + seg * 4] = *(const float4*)(in + (size_t)row * K + seg * 4);
            }
        }
        __syncthreads();

        for (int ks = w; ks < NKS; ks += 4) {
            ushort8v v;
#pragma unroll
            for (int j = 0; j < 8; ++j)
                v[j] = f2bf(ldsf[lc * KP + ks * 16 + hi * 8 + j]);
            *(ushort8v*)(out + ((size_t)t * NKS + ks) * 512 + lane * 8) = v;
        }
    } else {
        // ---------- weight pack (R8 wpack verbatim, 4 tiles per 256-thread block) ----------
        int q = (blockIdx.x - 11264) * 4 + (threadIdx.x >> 6);
        if (q >= 2304) return;
        int t = q;
        const float* W; unsigned short* out; int CT, P, N;
        if (t < 320)       {            W = Wch; out = pCH; CT = 8;  P = 8;  N = 256; }
        else if (t < 640)  { t -= 320;  W = Wup; out = pUP; CT = 8;  P = 8;  N = 256; }
        else if (t < 1920) { t -= 640;  W = Wcn; out = pCN; CT = 16; P = 16; N = 512; }
        else if (t < 2048) { t -= 1920; W = Wih; out = pIH; CT = 8;  P = 16; N = 256; }
        else               { t -= 2048; W = Win; out = pIN; CT = 16; P = 16; N = 512; }
        int per_d = CT * P;
        int d = t / per_d, r2 = t % per_d;
        int ct = r2 / P, p = r2 % P;
        int K = P * 16;
        const float* in = W + (size_t)d * K * N;
        int lane = threadIdx.x & 63, lc = lane & 31, hi = lane >> 5;
        ushort8v v;
#pragma unroll
        for (int j = 0; j < 8; ++j)
            v[j] = f2bf(in[(size_t)(p * 16 + hi * 8 + j) * N + ct * 32 + lc]);
        *(ushort8v*)(out + (((size_t)(d * CT + ct) * P + p) * 64 + lane) * 8) = v;
    }
}

// ---- fused HyperRHN: R15 STRUCTURE; sold prefetch moved before z; 1D interleaved grid ----
__global__ void __launch_bounds__(256, 4)
hyper_rhn_kernel(const float* __restrict__ x,
                 const float* __restrict__ sHyper,
                 const float* __restrict__ sNetwork,
                 const float* __restrict__ b_inp_h,
                 const float* __restrict__ b_cell_h,
                 const float* __restrict__ b_inp_n,
                 const float* __restrict__ b_cell_n,
                 const float* __restrict__ b_up,
                 const unsigned short* __restrict__ wtCellH,  // packed [5][8][8][64][8]
                 const unsigned short* __restrict__ wtUp,     // packed [5][8][8][64][8]
                 const unsigned short* __restrict__ wtCellN,  // packed [5][16][16][64][8]
                 const unsigned short* __restrict__ wtInpH,   // packed [8][16][64][8]
                 const unsigned short* __restrict__ wtInpN,   // packed [16][16][64][8]
                 const unsigned short* __restrict__ pH,       // packed states [5*1024][8][512]
                 const unsigned short* __restrict__ pN,       // packed states [5*1024][16][512]
                 const unsigned short* __restrict__ pX,       // packed x      [1024][16][512]
                 float* __restrict__ outMain,
                 float* __restrict__ outSH,
                 float* __restrict__ outSN) {
    __shared__ unsigned short sHlds[64 * 128];  // bf16 sH, XOR-swizzled (16 KB)

    const int bid  = blockIdx.x;
    const int l    = bid % 5;        // depth-interleaved: heavy l==0 blocks spread evenly
    const int bx   = bid / 5;
    const int r0   = bx * 64;
    const int tid  = threadIdx.x;
    const int w    = tid >> 6;
    const int lane = tid & 63;
    const int lc   = lane & 31;
    const int hi   = lane >> 5;

    const float* nB = sNetwork + ((size_t)l * B_ROWS + r0) * 256;
    const int ch = 32 * w + lc;
    const unsigned short* pHt = pH + ((size_t)(l * 1024 + 2 * bx) * 8) * 512;
    const unsigned short* pNt = pN + ((size_t)(l * 1024 + 2 * bx) * 16) * 512;
    const unsigned short* pXt = pX + ((size_t)(2 * bx) * 16) * 512;

    // ========== P1: WsH = sHyper @ W_cell_h (+ x @ W_inp_h at l==0) — R15 verbatim ==========
    f32x16 accHh[2] = {}, accHt[2] = {};
    {
#pragma unroll
        for (int ks = 0; ks < 8; ++ks) {
            bf16x8 af[2];
#pragma unroll
            for (int rf = 0; rf < 2; ++rf)
                af[rf] = *(const bf16x8*)(pHt + ((size_t)rf * 8 + ks) * 512 + lane * 8);
            bf16x8 bh_ = *(const bf16x8*)(wtCellH + (((size_t)l * 8 + w)     * 8 + ks) * 512 + lane * 8);
            bf16x8 bt_ = *(const bf16x8*)(wtCellH + (((size_t)l * 8 + 4 + w) * 8 + ks) * 512 + lane * 8);
#pragma unroll
            for (int rf = 0; rf < 2; ++rf) {
                accHh[rf] = __builtin_amdgcn_mfma_f32_32x32x16_bf16(af[rf], bh_, accHh[rf], 0, 0, 0);
                accHt[rf] = __builtin_amdgcn_mfma_f32_32x32x16_bf16(af[rf], bt_, accHt[rf], 0, 0, 0);
            }
        }
        if (l == 0) {
#pragma unroll
            for (int ks = 0; ks < 16; ++ks) {
                bf16x8 af[2];
#pragma unroll
                for (int rf = 0; rf < 2; ++rf)
                    af[rf] = *(const bf16x8*)(pXt + ((size_t)rf * 16 + ks) * 512 + lane * 8);
                bf16x8 bh_ = *(const bf16x8*)(wtInpH + ((size_t)(w)     * 16 + ks) * 512 + lane * 8);
                bf16x8 bt_ = *(const bf16x8*)(wtInpH + ((size_t)(4 + w) * 16 + ks) * 512 + lane * 8);
#pragma unroll
                for (int rf = 0; rf < 2; ++rf) {
                    accHh[rf] = __builtin_amdgcn_mfma_f32_32x32x16_bf16(af[rf], bh_, accHh[rf], 0, 0, 0);
                    accHt[rf] = __builtin_amdgcn_mfma_f32_32x32x16_bf16(af[rf], bt_, accHt[rf], 0, 0, 0);
                }
            }
        }
    }

    // ========== P2: hyper gate -> outSH + sHlds — R15 verbatim ==========
    {
        float bh = b_cell_h[l * 256 + ch]       + ((l == 0) ? b_inp_h[ch]       : 0.f);
        float bt = b_cell_h[l * 256 + 128 + ch] + ((l == 0) ? b_inp_h[128 + ch] : 0.f);
#pragma unroll
        for (int rf = 0; rf < 2; ++rf)
#pragma unroll
            for (int r = 0; r < 16; ++r) {
                int row = rf * 32 + (r & 3) + 8 * (r >> 2) + 4 * hi;
                size_t gr = (size_t)l * B_ROWS + r0 + row;
                float a  = accHh[rf][r] + bh;
                float g  = accHt[rf][r] + bt;
                float hh_ = fast_tanh(a);
                float tt_ = fast_sig(g);
                float sold = sHyper[gr * 128 + ch];
                float sh = hh_ * tt_ + sold * (1.0f - tt_);
                outSH[gr * 128 + ch] = sh;
                *(unsigned short*)((char*)sHlds + ((row * 256 + ch * 2) ^ ((row & 15) << 4))) = f2bf(sh);
            }
    }
    __syncthreads();

    // ========== 4 chunks (rf x cc): sold-prefetch, z, T, gate ==========
#pragma unroll 1
    for (int k = 0; k < 4; ++k) {
        const int rf   = k & 1;
        const int c    = w + 4 * (k >> 1);
        const int col  = 32 * c + lc;
        const int arow = rf * 32 + lc;

        // ---- sold prefetch FIRST: HBM latency hides under z + T MFMA chains ----
        f32x16 soldv;
#pragma unroll
        for (int r = 0; r < 16; ++r) {
            int row = rf * 32 + (r & 3) + 8 * (r >> 2) + 4 * hi;
            soldv[r] = nB[(size_t)row * 256 + col];
        }

        // ---- z = sH @ W_up ----
        f32x16 zac = {};
#pragma unroll
        for (int ks = 0; ks < 8; ++ks) {
            bf16x8 afz = *(const bf16x8*)((const char*)sHlds +
                           ((arow * 256 + ks * 32 + hi * 16) ^ ((arow & 15) << 4)));
            bf16x8 bz_ = *(const bf16x8*)(wtUp + (((size_t)l * 8 + c) * 8 + ks) * 512 + lane * 8);
            zac = __builtin_amdgcn_mfma_f32_32x32x16_bf16(afz, bz_, zac, 0, 0, 0);
        }

        // ---- T = sN @ W_cell_n (+ x @ W_inp_n at l==0): all streams contiguous ----
        f32x16 aTh = {}, aTt = {};
#pragma unroll
        for (int ks = 0; ks < 16; ++ks) {
            bf16x8 an = *(const bf16x8*)(pNt + ((size_t)rf * 16 + ks) * 512 + lane * 8);
            bf16x8 b0 = *(const bf16x8*)(wtCellN + (((size_t)l * 16 + c)     * 16 + ks) * 512 + lane * 8);
            bf16x8 b1 = *(const bf16x8*)(wtCellN + (((size_t)l * 16 + 8 + c) * 16 + ks) * 512 + lane * 8);
            aTh = __builtin_amdgcn_mfma_f32_32x32x16_bf16(an, b0, aTh, 0, 0, 0);
            aTt = __builtin_amdgcn_mfma_f32_32x32x16_bf16(an, b1, aTt, 0, 0, 0);
        }
        if (l == 0) {
#pragma unroll
            for (int ks = 0; ks < 16; ++ks) {
                bf16x8 ax = *(const bf16x8*)(pXt + ((size_t)rf * 16 + ks) * 512 + lane * 8);
                bf16x8 b0 = *(const bf16x8*)(wtInpN + ((size_t)(c)     * 16 + ks) * 512 + lane * 8);
                bf16x8 b1 = *(const bf16x8*)(wtInpN + ((size_t)(8 + c) * 16 + ks) * 512 + lane * 8);
                aTh = __builtin_amdgcn_mfma_f32_32x32x16_bf16(ax, b0, aTh, 0, 0, 0);
                aTt = __builtin_amdgcn_mfma_f32_32x32x16_bf16(ax, b1, aTt, 0, 0, 0);
            }
        }

        // ---- gate + dense stores — R15 verbatim ----
        float bz  = b_up[l * 256 + col];
        float bhn = b_cell_n[l * 512 + col]       + ((l == 0) ? b_inp_n[col]       : 0.f);
        float btn = b_cell_n[l * 512 + 256 + col] + ((l == 0) ? b_inp_n[256 + col] : 0.f);
#pragma unroll
        for (int r = 0; r < 16; ++r) {
            int row = rf * 32 + (r & 3) + 8 * (r >> 2) + 4 * hi;
            size_t gr = (size_t)l * B_ROWS + r0 + row;
            float zi   = zac[r] + bz;
            float tpre = zi * (aTh[r] + bhn);
            float upre = zi * (aTt[r] + btn);
            float hh_ = fast_tanh(tpre);
            float tt_ = fast_sig(upre);
            float sn = hh_ * tt_ + soldv[r] * (1.0f - tt_);
            outSN[gr * 256 + col] = sn;
            if (l == 4) outMain[(size_t)(r0 + row) * 256 + col] = sn;
        }
    }
}

extern "C" void kernel_launch(void* const* d_in, const int* in_sizes, int n_in,
                              void* d_out, int out_size, void* d_ws, size_t ws_size,
                              hipStream_t stream) {
    const float* x        = (const float*)d_in[0];
    const float* sHyper   = (const float*)d_in[1];
    const float* sNetwork = (const float*)d_in[2];
    const float* W_inp_h  = (const float*)d_in[3];
    const float* b_inp_h  = (const float*)d_in[4];
    const float* W_cell_h = (const float*)d_in[5];
    const float* b_cell_h = (const float*)d_in[6];
    const float* W_inp_n  = (const float*)d_in[7];
    const float* b_inp_n  = (const float*)d_in[8];
    const float* W_cell_n = (const float*)d_in[9];
    const float* b_cell_n = (const float*)d_in[10];
    const float* W_up     = (const float*)d_in[11];
    const float* b_up     = (const float*)d_in[12];

    unsigned short* ws = (unsigned short*)d_ws;
    unsigned short* wtCellH = ws;                  // 163840
    unsigned short* wtUp    = ws + 163840;         // 163840
    unsigned short* wtCellN = ws + 327680;         // 655360
    unsigned short* wtInpH  = ws + 983040;         // 65536
    unsigned short* wtInpN  = ws + 1048576;        // 131072
    unsigned short* pH      = ws + 1179648;        // 20971520
    unsigned short* pN      = ws + 22151168;       // 41943040
    unsigned short* pX      = ws + 64094208;       // 8388608

    prep_all<<<11840, 256, 0, stream>>>(sHyper, sNetwork, x,
                                        W_cell_h, W_up, W_cell_n, W_inp_h, W_inp_n,
                                        pH, pN, pX,
                                        wtCellH, wtUp, wtCellN, wtInpH, wtInpN);

    float* outMain = (float*)d_out;
    float* outSH = outMain + (size_t)B_ROWS * 256;               // [5][B][128]
    float* outSN = outSH + (size_t)NDEPTH * B_ROWS * 128;        // [5][B][256]

    hyper_rhn_kernel<<<2560, 256, 0, stream>>>(
        x, sHyper, sNetwork,
        b_inp_h, b_cell_h, b_inp_n, b_cell_n, b_up,
        wtCellH, wtUp, wtCellN, wtInpH, wtInpN,
        pH, pN, pX,
        outMain, outSH, outSN);
}

// Round 17
// 324.857 us; speedup vs baseline: 1.0927x; 1.0927x over previous
//
#include <hip/hip_runtime.h>
#include <hip/hip_bf16.h>

#define B_ROWS 32768
#define NDEPTH 5

typedef float  f32x16 __attribute__((ext_vector_type(16)));
typedef short  bf16x8 __attribute__((ext_vector_type(8)));
typedef unsigned short ushort8v __attribute__((ext_vector_type(8)));

__device__ __forceinline__ unsigned short f2bf(float f) {
    __hip_bfloat16 h = __float2bfloat16(f);   // RNE; v_cvt_pk_bf16_f32
    return __builtin_bit_cast(unsigned short, h);
}

// division-free gates: v_exp + v_rcp only (R15-verified)
__device__ __forceinline__ float fast_sig(float x) {
    x = fminf(fmaxf(x, -30.f), 30.f);
    float e = __expf(-x);
    return __builtin_amdgcn_rcpf(1.0f + e);
}
__device__ __forceinline__ float fast_tanh(float x) {
    x = fminf(fmaxf(x, -15.f), 15.f);
    float e = __expf(2.0f * x);
    return 1.0f - 2.0f * __builtin_amdgcn_rcpf(e + 1.0f);
}

// ---- ONE prep launch (R16-verified, −17 µs vs two launches) ----
// blocks [0, 11264): pack states; blocks [11264, 11840): 4 weight tiles each.
__global__ void __launch_bounds__(256, 2)
prep_all(const float* __restrict__ sHyper, const float* __restrict__ sNetwork,
         const float* __restrict__ x,
         const float* __restrict__ Wch, const float* __restrict__ Wup,
         const float* __restrict__ Wcn, const float* __restrict__ Wih,
         const float* __restrict__ Win,
         unsigned short* __restrict__ pH, unsigned short* __restrict__ pN,
         unsigned short* __restrict__ pX,
         unsigned short* __restrict__ pCH, unsigned short* __restrict__ pUP,
         unsigned short* __restrict__ pCN, unsigned short* __restrict__ pIH,
         unsigned short* __restrict__ pIN) {
    __shared__ float ldsf[32 * 257];
    if (blockIdx.x < 11264) {
        // ---------- state pack (R13 spack verbatim) ----------
        int t = blockIdx.x;
        const float* src; unsigned short* out; int K;
        if (t < 5120)        {             src = sHyper;   out = pH; K = 128; }
        else if (t < 10240)  { t -= 5120;  src = sNetwork; out = pN; K = 256; }
        else                 { t -= 10240; src = x;        out = pX; K = 256; }
        const int NKS = K / 16, KP = K + 1;
        const float* in = src + (size_t)t * 32 * K;
        const int tid = threadIdx.x, w = tid >> 6, lane = tid & 63;
        const int lc = lane & 31, hi = lane >> 5;

        if (K == 256) {
#pragma unroll
            for (int it = 0; it < 8; ++it) {
                int u = it * 256 + tid;
                int row = u >> 6, seg = u & 63;
                *(float4*)&ldsf[row * KP + seg * 4] = *(const float4*)(in + (size_t)row * K + seg * 4);
            }
        } else {
#pragma unroll
            for (int it = 0; it < 4; ++it) {
                int u = it * 256 + tid;
                int row = u >> 5, seg = u & 31;
                *(float4*)&ldsf[row * KP + seg * 4] = *(const float4*)(in + (size_t)row * K + seg * 4);
            }
        }
        __syncthreads();

        for (int ks = w; ks < NKS; ks += 4) {
            ushort8v v;
#pragma unroll
            for (int j = 0; j < 8; ++j)
                v[j] = f2bf(ldsf[lc * KP + ks * 16 + hi * 8 + j]);
            *(ushort8v*)(out + ((size_t)t * NKS + ks) * 512 + lane * 8) = v;
        }
    } else {
        // ---------- weight pack (R8 wpack verbatim, 4 tiles per 256-thread block) ----------
        int q = (blockIdx.x - 11264) * 4 + (threadIdx.x >> 6);
        if (q >= 2304) return;
        int t = q;
        const float* W; unsigned short* out; int CT, P, N;
        if (t < 320)       {            W = Wch; out = pCH; CT = 8;  P = 8;  N = 256; }
        else if (t < 640)  { t -= 320;  W = Wup; out = pUP; CT = 8;  P = 8;  N = 256; }
        else if (t < 1920) { t -= 640;  W = Wcn; out = pCN; CT = 16; P = 16; N = 512; }
        else if (t < 2048) { t -= 1920; W = Wih; out = pIH; CT = 8;  P = 16; N = 256; }
        else               { t -= 2048; W = Win; out = pIN; CT = 16; P = 16; N = 512; }
        int per_d = CT * P;
        int d = t / per_d, r2 = t % per_d;
        int ct = r2 / P, p = r2 % P;
        int K = P * 16;
        const float* in = W + (size_t)d * K * N;
        int lane = threadIdx.x & 63, lc = lane & 31, hi = lane >> 5;
        ushort8v v;
#pragma unroll
        for (int j = 0; j < 8; ++j)
            v[j] = f2bf(in[(size_t)(p * 16 + hi * 8 + j) * N + ct * 32 + lc]);
        *(ushort8v*)(out + (((size_t)(d * CT + ct) * P + p) * 64 + lane) * 8) = v;
    }
}

// ---- fused HyperRHN: R15 MAIN KERNEL BYTE-FOR-BYTE (2D grid, sold after z) ----
__global__ void __launch_bounds__(256, 4)
hyper_rhn_kernel(const float* __restrict__ x,
                 const float* __restrict__ sHyper,
                 const float* __restrict__ sNetwork,
                 const float* __restrict__ b_inp_h,
                 const float* __restrict__ b_cell_h,
                 const float* __restrict__ b_inp_n,
                 const float* __restrict__ b_cell_n,
                 const float* __restrict__ b_up,
                 const unsigned short* __restrict__ wtCellH,  // packed [5][8][8][64][8]
                 const unsigned short* __restrict__ wtUp,     // packed [5][8][8][64][8]
                 const unsigned short* __restrict__ wtCellN,  // packed [5][16][16][64][8]
                 const unsigned short* __restrict__ wtInpH,   // packed [8][16][64][8]
                 const unsigned short* __restrict__ wtInpN,   // packed [16][16][64][8]
                 const unsigned short* __restrict__ pH,       // packed states [5*1024][8][512]
                 const unsigned short* __restrict__ pN,       // packed states [5*1024][16][512]
                 const unsigned short* __restrict__ pX,       // packed x      [1024][16][512]
                 float* __restrict__ outMain,
                 float* __restrict__ outSH,
                 float* __restrict__ outSN) {
    __shared__ unsigned short sHlds[64 * 128];  // bf16 sH, XOR-swizzled (16 KB)

    const int l    = blockIdx.y;
    const int bx   = blockIdx.x;
    const int r0   = bx * 64;
    const int tid  = threadIdx.x;
    const int w    = tid >> 6;
    const int lane = tid & 63;
    const int lc   = lane & 31;
    const int hi   = lane >> 5;

    const float* nB = sNetwork + ((size_t)l * B_ROWS + r0) * 256;
    const int ch = 32 * w + lc;
    const unsigned short* pHt = pH + ((size_t)(l * 1024 + 2 * bx) * 8) * 512;
    const unsigned short* pNt = pN + ((size_t)(l * 1024 + 2 * bx) * 16) * 512;
    const unsigned short* pXt = pX + ((size_t)(2 * bx) * 16) * 512;

    // ========== P1: WsH = sHyper @ W_cell_h (+ x @ W_inp_h at l==0) ==========
    f32x16 accHh[2] = {}, accHt[2] = {};
    {
#pragma unroll
        for (int ks = 0; ks < 8; ++ks) {
            bf16x8 af[2];
#pragma unroll
            for (int rf = 0; rf < 2; ++rf)
                af[rf] = *(const bf16x8*)(pHt + ((size_t)rf * 8 + ks) * 512 + lane * 8);
            bf16x8 bh_ = *(const bf16x8*)(wtCellH + (((size_t)l * 8 + w)     * 8 + ks) * 512 + lane * 8);
            bf16x8 bt_ = *(const bf16x8*)(wtCellH + (((size_t)l * 8 + 4 + w) * 8 + ks) * 512 + lane * 8);
#pragma unroll
            for (int rf = 0; rf < 2; ++rf) {
                accHh[rf] = __builtin_amdgcn_mfma_f32_32x32x16_bf16(af[rf], bh_, accHh[rf], 0, 0, 0);
                accHt[rf] = __builtin_amdgcn_mfma_f32_32x32x16_bf16(af[rf], bt_, accHt[rf], 0, 0, 0);
            }
        }
        if (l == 0) {
#pragma unroll
            for (int ks = 0; ks < 16; ++ks) {
                bf16x8 af[2];
#pragma unroll
                for (int rf = 0; rf < 2; ++rf)
                    af[rf] = *(const bf16x8*)(pXt + ((size_t)rf * 16 + ks) * 512 + lane * 8);
                bf16x8 bh_ = *(const bf16x8*)(wtInpH + ((size_t)(w)     * 16 + ks) * 512 + lane * 8);
                bf16x8 bt_ = *(const bf16x8*)(wtInpH + ((size_t)(4 + w) * 16 + ks) * 512 + lane * 8);
#pragma unroll
                for (int rf = 0; rf < 2; ++rf) {
                    accHh[rf] = __builtin_amdgcn_mfma_f32_32x32x16_bf16(af[rf], bh_, accHh[rf], 0, 0, 0);
                    accHt[rf] = __builtin_amdgcn_mfma_f32_32x32x16_bf16(af[rf], bt_, accHt[rf], 0, 0, 0);
                }
            }
        }
    }

    // ========== P2: hyper gate -> outSH + sHlds ==========
    {
        float bh = b_cell_h[l * 256 + ch]       + ((l == 0) ? b_inp_h[ch]       : 0.f);
        float bt = b_cell_h[l * 256 + 128 + ch] + ((l == 0) ? b_inp_h[128 + ch] : 0.f);
#pragma unroll
        for (int rf = 0; rf < 2; ++rf)
#pragma unroll
            for (int r = 0; r < 16; ++r) {
                int row = rf * 32 + (r & 3) + 8 * (r >> 2) + 4 * hi;
                size_t gr = (size_t)l * B_ROWS + r0 + row;
                float a  = accHh[rf][r] + bh;
                float g  = accHt[rf][r] + bt;
                float hh_ = fast_tanh(a);
                float tt_ = fast_sig(g);
                float sold = sHyper[gr * 128 + ch];
                float sh = hh_ * tt_ + sold * (1.0f - tt_);
                outSH[gr * 128 + ch] = sh;
                *(unsigned short*)((char*)sHlds + ((row * 256 + ch * 2) ^ ((row & 15) << 4))) = f2bf(sh);
            }
    }
    __syncthreads();

    // ========== 4 chunks (rf x cc): z, sold, T, gate — R15 verbatim ==========
#pragma unroll 1
    for (int k = 0; k < 4; ++k) {
        const int rf   = k & 1;
        const int c    = w + 4 * (k >> 1);
        const int col  = 32 * c + lc;
        const int arow = rf * 32 + lc;

        // ---- z = sH @ W_up ----
        f32x16 zac = {};
#pragma unroll
        for (int ks = 0; ks < 8; ++ks) {
            bf16x8 afz = *(const bf16x8*)((const char*)sHlds +
                           ((arow * 256 + ks * 32 + hi * 16) ^ ((arow & 15) << 4)));
            bf16x8 bz_ = *(const bf16x8*)(wtUp + (((size_t)l * 8 + c) * 8 + ks) * 512 + lane * 8);
            zac = __builtin_amdgcn_mfma_f32_32x32x16_bf16(afz, bz_, zac, 0, 0, 0);
        }

        // ---- prefetch sold (dense 128-B loads) ----
        f32x16 soldv;
#pragma unroll
        for (int r = 0; r < 16; ++r) {
            int row = rf * 32 + (r & 3) + 8 * (r >> 2) + 4 * hi;
            soldv[r] = nB[(size_t)row * 256 + col];
        }

        // ---- T = sN @ W_cell_n (+ x @ W_inp_n at l==0): all streams contiguous ----
        f32x16 aTh = {}, aTt = {};
#pragma unroll
        for (int ks = 0; ks < 16; ++ks) {
            bf16x8 an = *(const bf16x8*)(pNt + ((size_t)rf * 16 + ks) * 512 + lane * 8);
            bf16x8 b0 = *(const bf16x8*)(wtCellN + (((size_t)l * 16 + c)     * 16 + ks) * 512 + lane * 8);
            bf16x8 b1 = *(const bf16x8*)(wtCellN + (((size_t)l * 16 + 8 + c) * 16 + ks) * 512 + lane * 8);
            aTh = __builtin_amdgcn_mfma_f32_32x32x16_bf16(an, b0, aTh, 0, 0, 0);
            aTt = __builtin_amdgcn_mfma_f32_32x32x16_bf16(an, b1, aTt, 0, 0, 0);
        }
        if (l == 0) {
#pragma unroll
            for (int ks = 0; ks < 16; ++ks) {
                bf16x8 ax = *(const bf16x8*)(pXt + ((size_t)rf * 16 + ks) * 512 + lane * 8);
                bf16x8 b0 = *(const bf16x8*)(wtInpN + ((size_t)(c)     * 16 + ks) * 512 + lane * 8);
                bf16x8 b1 = *(const bf16x8*)(wtInpN + ((size_t)(8 + c) * 16 + ks) * 512 + lane * 8);
                aTh = __builtin_amdgcn_mfma_f32_32x32x16_bf16(ax, b0, aTh, 0, 0, 0);
                aTt = __builtin_amdgcn_mfma_f32_32x32x16_bf16(ax, b1, aTt, 0, 0, 0);
            }
        }

        // ---- gate + dense stores ----
        float bz  = b_up[l * 256 + col];
        float bhn = b_cell_n[l * 512 + col]       + ((l == 0) ? b_inp_n[col]       : 0.f);
        float btn = b_cell_n[l * 512 + 256 + col] + ((l == 0) ? b_inp_n[256 + col] : 0.f);
#pragma unroll
        for (int r = 0; r < 16; ++r) {
            int row = rf * 32 + (r & 3) + 8 * (r >> 2) + 4 * hi;
            size_t gr = (size_t)l * B_ROWS + r0 + row;
            float zi   = zac[r] + bz;
            float tpre = zi * (aTh[r] + bhn);
            float upre = zi * (aTt[r] + btn);
            float hh_ = fast_tanh(tpre);
            float tt_ = fast_sig(upre);
            float sn = hh_ * tt_ + soldv[r] * (1.0f - tt_);
            outSN[gr * 256 + col] = sn;
            if (l == 4) outMain[(size_t)(r0 + row) * 256 + col] = sn;
        }
    }
}

extern "C" void kernel_launch(void* const* d_in, const int* in_sizes, int n_in,
                              void* d_out, int out_size, void* d_ws, size_t ws_size,
                              hipStream_t stream) {
    const float* x        = (const float*)d_in[0];
    const float* sHyper   = (const float*)d_in[1];
    const float* sNetwork = (const float*)d_in[2];
    const float* W_inp_h  = (const float*)d_in[3];
    const float* b_inp_h  = (const float*)d_in[4];
    const float* W_cell_h = (const float*)d_in[5];
    const float* b_cell_h = (const float*)d_in[6];
    const float* W_inp_n  = (const float*)d_in[7];
    const float* b_inp_n  = (const float*)d_in[8];
    const float* W_cell_n = (const float*)d_in[9];
    const float* b_cell_n = (const float*)d_in[10];
    const float* W_up     = (const float*)d_in[11];
    const float* b_up     = (const float*)d_in[12];

    unsigned short* ws = (unsigned short*)d_ws;
    unsigned short* wtCellH = ws;                  // 163840
    unsigned short* wtUp    = ws + 163840;         // 163840
    unsigned short* wtCellN = ws + 327680;         // 655360
    unsigned short* wtInpH  = ws + 983040;         // 65536
    unsigned short* wtInpN  = ws + 1048576;        // 131072
    unsigned short* pH      = ws + 1179648;        // 20971520
    unsigned short* pN      = ws + 22151168;       // 41943040
    unsigned short* pX      = ws + 64094208;       // 8388608

    prep_all<<<11840, 256, 0, stream>>>(sHyper, sNetwork, x,
                                        W_cell_h, W_up, W_cell_n, W_inp_h, W_inp_n,
                                        pH, pN, pX,
                                        wtCellH, wtUp, wtCellN, wtInpH, wtInpN);

    float* outMain = (float*)d_out;
    float* outSH = outMain + (size_t)B_ROWS * 256;               // [5][B][128]
    float* outSN = outSH + (size_t)NDEPTH * B_ROWS * 128;        // [5][B][256]

    hyper_rhn_kernel<<<dim3(B_ROWS / 64, NDEPTH), 256, 0, stream>>>(
        x, sHyper, sNetwork,
        b_inp_h, b_cell_h, b_inp_n, b_cell_n, b_up,
        wtCellH, wtUp, wtCellN, wtInpH, wtInpN,
        pH, pN, pX,
        outMain, outSH, outSN);
}